// Round 4
// baseline (169.441 us; speedup 1.0000x reference)
//
#include <hip/hip_runtime.h>

#define NTOK 65536
#define DIN 128
#define DH 256
#define DOUT 128
#define NEXP 8
#define NPAIR 28
#define CAP 12288
#define NBEXP 256     // persistent expert blocks, 1 per CU
#define TAUF 5.0f
#define CSTRIDE 32    // cnt padded: one counter per 128 B

typedef __attribute__((ext_vector_type(8))) short short8;
typedef __attribute__((ext_vector_type(4))) float f32x4;

// ---- workspace layout (bytes) ----
#define OFF_CNT  0                              // 28 ints @ stride 32 ints
#define OFF_WG   4096                           // 1024 f32
#define OFF_BG   8192                           // 8 f32
#define OFF_W1F  8448                           // 8*128*256 bf16 = 524288 (slab layout)
#define OFF_W2F  (OFF_W1F + NEXP*DIN*DH*2)      // 524288 (slab layout)
#define OFF_L    (OFF_W2F + NEXP*DH*DOUT*2)     // 28*12288*16 = 5505024

__device__ __forceinline__ unsigned short f2bf(float f) {
  union { float f; unsigned u; } v; v.f = f;
  unsigned u = v.u;
  return (unsigned short)((u + 0x7FFFu + ((u >> 16) & 1u)) >> 16);
}

// ---- kernel 1: weight re-layout into per-(e,quarter) contiguous 16KB slabs ----
// W1P[e][qd]: [g=kk*4+q][hcl 64][8]  value = W1[e][k=kk*32+q*8+s][hc=qd*64+hcl]
// W2P[e][qd]: [g=kkl*4+q][oc 128][8] value = W2[e][k=qd*64+kkl*32+q*8+s][oc]
__global__ void k_prep(const float* __restrict__ W1, const float* __restrict__ W2,
                       unsigned short* __restrict__ W1F, unsigned short* __restrict__ W2F,
                       const float* __restrict__ Wp, const float* __restrict__ bp,
                       const float* __restrict__ Ee, float* __restrict__ Wg,
                       float* __restrict__ bg, int* __restrict__ cnt,
                       float* __restrict__ aux) {
  __shared__ float sl[8704];
  int b = blockIdx.x, t = threadIdx.x;
  if (b == 64) {
    for (int i = 0; i < 32; i++) sl[t + i * 256] = Wp[t + i * 256];
    sl[8192 + t] = Ee[t];
    sl[8448 + t] = Ee[256 + t];
    __syncthreads();
    for (int i = 0; i < 4; i++) {
      int o = t + i * 256;
      int k = o >> 3, e = o & 7;
      float s = 0.f;
      #pragma unroll 8
      for (int l = 0; l < 64; l++) s += sl[k * 64 + l] * sl[8192 + l * 8 + e];
      Wg[o] = s;
    }
    if (t < 8) {
      float s = 0.f;
      for (int l = 0; l < 64; l++) s += bp[l] * sl[8192 + l * 8 + t];
      bg[t] = s;
    }
    if (t < NPAIR) cnt[t * CSTRIDE] = 0;
    if (t == 255) aux[0] = 0.f;
    return;
  }
  if (b < 32) {
    int e = b >> 2, kk = b & 3;                 // W1 k-rows [kk*32, +32), all 256 hc
    const float* src = W1 + e * (DIN * DH) + kk * 32 * DH;
    for (int i = 0; i < 32; i++) {
      int idx = t + i * 256;
      int r = idx >> 8, c = idx & 255;
      sl[r * 257 + c] = src[idx];
    }
    __syncthreads();
    for (int i = 0; i < 32; i++) {
      int o = t + i * 256;
      int qd = o >> 11, qq = (o >> 9) & 3, hcl = (o >> 3) & 63, s = o & 7;
      float v = sl[(qq * 8 + s) * 257 + qd * 64 + hcl];
      W1F[(e * 4 + qd) * 8192 + (kk * 4 + qq) * 512 + hcl * 8 + s] = f2bf(v);
    }
  } else {
    int bb = b - 32;
    int e = bb >> 2, qd = bb & 3;               // W2 k-rows [qd*64, +64), all 128 oc
    const float* src = W2 + e * (DH * DOUT) + qd * 64 * DOUT;
    for (int i = 0; i < 32; i++) {
      int idx = t + i * 256;
      int r = idx >> 7, c = idx & 127;
      sl[r * 129 + c] = src[idx];
    }
    __syncthreads();
    for (int i = 0; i < 32; i++) {
      int o = t + i * 256;
      int g = o >> 10, oc = (o >> 3) & 127, s = o & 7;
      int kl = (g >> 2) * 32 + (g & 3) * 8 + s;
      W2F[(e * 4 + qd) * 8192 + g * 1024 + oc * 8 + s] = f2bf(sl[kl * 129 + oc]);
    }
  }
}

// ---- kernel 2: gate v3 — 128 blocks x 512 thr, coalesced LDS staging (2 halves),
// thread-per-token dot from LDS, 128-deep atomic chains, coalesced pout ----
__global__ void __launch_bounds__(512) k_gate(
    const float* __restrict__ x, const float* __restrict__ Wg, const float* __restrict__ bg,
    float* __restrict__ pout, int* __restrict__ cnt, uint4* __restrict__ lst) {
  __shared__ float xg[256 * 132];     // 135168 B
  __shared__ float wgl[1024];
  __shared__ float pg[4096];          // [512 tok][8]
  __shared__ float bgl[8];
  __shared__ int lc[NPAIR], lb[NPAIR];
  int t = threadIdx.x, b = blockIdx.x;
  if (t < 256) *(float4*)&wgl[t * 4] = ((const float4*)Wg)[t];
  if (t < 8) bgl[t] = bg[t];
  if (t < NPAIR) lc[t] = 0;
  int myPid = 0; unsigned uwA = 0, uwB = 0;
  for (int h = 0; h < 2; h++) {
    __syncthreads();                  // prev-half compute done / init visible
    const float4* x4 = (const float4*)(x + ((size_t)b * 512 + h * 256) * DIN);
    #pragma unroll
    for (int i = 0; i < 16; i++) {
      int idx = i * 512 + t;
      int r = idx >> 5, c4 = idx & 31;
      *(float4*)&xg[r * 132 + c4 * 4] = x4[idx];
    }
    __syncthreads();
    if ((t >> 8) == h) {
      int tl = t & 255;
      float acc[8];
      #pragma unroll
      for (int e = 0; e < 8; e++) acc[e] = bgl[e];
      #pragma unroll 8
      for (int k4 = 0; k4 < 32; k4++) {
        float4 xv = *(const float4*)&xg[tl * 132 + k4 * 4];
        #pragma unroll
        for (int j = 0; j < 4; j++) {
          float xs_ = (j == 0) ? xv.x : (j == 1) ? xv.y : (j == 2) ? xv.z : xv.w;
          float4 wa = *(const float4*)&wgl[(k4 * 4 + j) * 8];
          float4 wb = *(const float4*)&wgl[(k4 * 4 + j) * 8 + 4];
          acc[0] += xs_ * wa.x; acc[1] += xs_ * wa.y; acc[2] += xs_ * wa.z; acc[3] += xs_ * wa.w;
          acc[4] += xs_ * wb.x; acc[5] += xs_ * wb.y; acc[6] += xs_ * wb.z; acc[7] += xs_ * wb.w;
        }
      }
      float p[8];
      #pragma unroll
      for (int e = 0; e < 8; e++) p[e] = 1.f / (1.f + expf(-acc[e] / TAUF));
      #pragma unroll
      for (int e = 0; e < 8; e++) pg[t * 8 + e] = p[e];
      int i0 = 0; float v0 = -1.f;
      #pragma unroll
      for (int e = 0; e < 8; e++) if (p[e] > v0) { v0 = p[e]; i0 = e; }
      int i1 = -1; float v1 = -1.f;
      #pragma unroll
      for (int e = 0; e < 8; e++) if (e != i0 && p[e] > v1) { v1 = p[e]; i1 = e; }
      float s = v0 + v1 + 1e-10f;
      float w0 = v0 / s, w1 = v1 / s;
      int eA, eB; float wA, wB;
      if (i0 < i1) { eA = i0; eB = i1; wA = w0; wB = w1; }
      else         { eA = i1; eB = i0; wA = w1; wB = w0; }
      myPid = 7 * eA - (eA * (eA - 1)) / 2 + (eB - eA - 1);
      union { float f; unsigned u; } ua, ub; ua.f = wA; ub.f = wB;
      uwA = ua.u; uwB = ub.u;
    }
  }
  unsigned pos = (unsigned)atomicAdd(&lc[myPid], 1);
  __syncthreads();
  if (t < NPAIR) lb[t] = atomicAdd(&cnt[t * CSTRIDE], lc[t]);
  __syncthreads();
  int gi = lb[myPid] + (int)pos;
  if (gi < CAP) lst[myPid * CAP + gi] = make_uint4((unsigned)(b * 512 + t), uwA, uwB, 0u);
  const int base = b * 4096;
  #pragma unroll
  for (int j = 0; j < 8; j++) pout[base + j * 512 + t] = pg[j * 512 + t];
}

// ---- kernel 3: expert v5 — 256-token tiles, LDS weight-slab ring, 1 block/CU.
// 8 rounds/tile (2 experts x 4 DH-quarters): G1 (hidden quarter, swapped operands:
// D rows=hcol, cols=token) -> hs pre-scaled by gate weight; G2 accumulates K-quarter
// into acc2 (D rows=outcol, cols=token). Next round's 16KB slab reg-staged under
// current GEMM (issue-early/write-late). Weight traffic: 1 KB/token. ----
__global__ void __launch_bounds__(512, 2) k_expert(
    const float* __restrict__ x,
    const unsigned short* __restrict__ W1F, const unsigned short* __restrict__ W2F,
    const float* __restrict__ b1, const float* __restrict__ b2,
    const int* __restrict__ cnt, const uint4* __restrict__ lst,
    float* __restrict__ out) {
  __shared__ int cs[NPAIR];
  __shared__ __align__(16) unsigned short xs[256 * 128];   // 64 KB, XOR-swizzled
  __shared__ __align__(16) unsigned short hs[256 * 64];    // 32 KB, XOR-swizzled
  __shared__ __align__(16) unsigned short WS[3][8192];     // 3 x 16 KB slab ring
  __shared__ int toks[256];
  __shared__ float wabL[512];                              // [0..255]=wA, [256..]=wB
  __shared__ float b1L[512];
  __shared__ float b2L[256];
  int t = threadIdx.x;
  int w = t >> 6, lane = t & 63;
  int q = lane >> 4, n16 = lane & 15;
  int wh = w >> 2;     // hc-half (G1) / oc-half (G2)
  int wt = w & 3;      // 64-token group
  const f32x4 vz = {0.f, 0.f, 0.f, 0.f};
  if (t < NPAIR) { int c = cnt[t * CSTRIDE]; cs[t] = (c > CAP) ? CAP : c; }
  __syncthreads();
  int F = 0, P = 0;
  #pragma unroll
  for (int bb = 0; bb < NPAIR; bb++) { F += cs[bb] >> 8; P += (cs[bb] & 255) ? 1 : 0; }

  for (int gid = blockIdx.x; gid < F + P; gid += NBEXP) {
    // resolve: full 256-tiles first (gid < F), then partial tiles
    int bsel = 0, start = 0, cval = 0;
    if (gid < F) {
      int cum = 0;
      #pragma unroll
      for (int bb = 0; bb < NPAIR; bb++) {
        int nf = cs[bb] >> 8;
        if (gid >= cum && gid < cum + nf) { bsel = bb; start = (gid - cum) * 256; cval = 256; }
        cum += nf;
      }
    } else {
      int pi = gid - F, cum = 0;
      #pragma unroll
      for (int bb = 0; bb < NPAIR; bb++) {
        int hasP = (cs[bb] & 255) ? 1 : 0;
        if (hasP && pi == cum) { bsel = bb; start = cs[bb] & ~255; cval = cs[bb] - start; }
        cum += hasP;
      }
    }
    int eA = 0, eB = 1;
    { int r = bsel;
      #pragma unroll
      for (int a = 0; a < 7; a++) { int span = 7 - a; if (r < span) { eA = a; eB = a + 1 + r; break; } r -= span; } }

    // ---- prologue: lists, biases ----
    if (t < 256) {
      uint4 en = make_uint4(0u, 0u, 0u, 0u);
      if (t < cval) en = lst[bsel * CAP + start + t];
      toks[t] = (t < cval) ? (int)en.x : 0;
      union { unsigned u; float f; } ua, ub; ua.u = en.y; ub.u = en.z;
      wabL[t] = (t < cval) ? ua.f : 0.f;
      wabL[256 + t] = (t < cval) ? ub.f : 0.f;
      b2L[t] = b2[((t < 128) ? eA : eB) * DOUT + (t & 127)];
    }
    b1L[t] = b1[((t < 256) ? eA : eB) * DH + (t & 255)];
    __syncthreads();
    // ---- gather x -> xs (bf16, swizzled) + stage slabs for round 0 ----
    {
      const unsigned short* s0 = W1F + (eA * 4 + 0) * 8192;
      const unsigned short* s1 = W2F + (eA * 4 + 0) * 8192;
      short8 w0a = *(const short8*)(s0 + t * 16);
      short8 w0b = *(const short8*)(s0 + t * 16 + 8);
      short8 w1a = *(const short8*)(s1 + t * 16);
      short8 w1b = *(const short8*)(s1 + t * 16 + 8);
      #pragma unroll
      for (int i = 0; i < 16; i++) {
        int idx = i * 512 + t;
        int r = idx >> 5, c4 = idx & 31;
        float4 f = *(const float4*)(x + (size_t)toks[r] * DIN + c4 * 4);
        unsigned u0 = (unsigned)f2bf(f.x) | ((unsigned)f2bf(f.y) << 16);
        unsigned u1 = (unsigned)f2bf(f.z) | ((unsigned)f2bf(f.w) << 16);
        int si = (r * 128 + c4 * 4) ^ ((r & 7) << 3);
        *(uint2*)(xs + si) = make_uint2(u0, u1);
      }
      *(short8*)(WS[0] + t * 16) = w0a;  *(short8*)(WS[0] + t * 16 + 8) = w0b;
      *(short8*)(WS[1] + t * 16) = w1a;  *(short8*)(WS[1] + t * 16 + 8) = w1b;
    }
    __syncthreads();

    f32x4 acc2[4][4];
    #pragma unroll
    for (int mt = 0; mt < 4; mt++)
      #pragma unroll
      for (int nt = 0; nt < 4; nt++) acc2[mt][nt] = vz;

    #pragma unroll
    for (int r8 = 0; r8 < 8; r8++) {
      const int ei = r8 >> 2;                        // 0=A, 1=B (LDS bias/wab index)
      const int qd = r8 & 3;
      const int iW1 = (2 * r8) % 3, iW2 = (2 * r8 + 1) % 3, iSp = (2 * r8 + 2) % 3;
      // ---- G1: hs = wab * relu(W1q^T-frag MFMA xs) ----
      short8 sa, sb;
      if (r8 < 7) {
        const unsigned short* ns = W1F + (((r8 + 1 < 4) ? eA : eB) * 4 + ((r8 + 1) & 3)) * 8192;
        sa = *(const short8*)(ns + t * 16);
        sb = *(const short8*)(ns + t * 16 + 8);
      }
      f32x4 acc1[2][4];
      #pragma unroll
      for (int mt = 0; mt < 2; mt++)
        #pragma unroll
        for (int nt = 0; nt < 4; nt++) acc1[mt][nt] = vz;
      #pragma unroll
      for (int kk = 0; kk < 4; kk++) {
        short8 af0 = *(const short8*)(WS[iW1] + ((kk * 4 + q) * 64 + wh * 32 + n16) * 8);
        short8 af1 = *(const short8*)(WS[iW1] + ((kk * 4 + q) * 64 + wh * 32 + 16 + n16) * 8);
        short8 bx[4];
        #pragma unroll
        for (int nt = 0; nt < 4; nt++) {
          int tok = wt * 64 + nt * 16 + n16;
          bx[nt] = *(const short8*)(xs + ((tok * 128 + kk * 32 + q * 8) ^ ((tok & 7) << 3)));
        }
        #pragma unroll
        for (int nt = 0; nt < 4; nt++) {
          acc1[0][nt] = __builtin_amdgcn_mfma_f32_16x16x32_bf16(af0, bx[nt], acc1[0][nt], 0, 0, 0);
          acc1[1][nt] = __builtin_amdgcn_mfma_f32_16x16x32_bf16(af1, bx[nt], acc1[1][nt], 0, 0, 0);
        }
      }
      #pragma unroll
      for (int mt = 0; mt < 2; mt++) {
        float4 b1f = *(const float4*)&b1L[ei * 256 + qd * 64 + wh * 32 + mt * 16 + q * 4];
        #pragma unroll
        for (int nt = 0; nt < 4; nt++) {
          int tok = wt * 64 + nt * 16 + n16;
          float wv = wabL[ei * 256 + tok];
          float v0 = fmaxf(acc1[mt][nt][0] + b1f.x, 0.f) * wv;
          float v1 = fmaxf(acc1[mt][nt][1] + b1f.y, 0.f) * wv;
          float v2 = fmaxf(acc1[mt][nt][2] + b1f.z, 0.f) * wv;
          float v3 = fmaxf(acc1[mt][nt][3] + b1f.w, 0.f) * wv;
          unsigned u0 = (unsigned)f2bf(v0) | ((unsigned)f2bf(v1) << 16);
          unsigned u1 = (unsigned)f2bf(v2) | ((unsigned)f2bf(v3) << 16);
          int si = (tok * 64 + wh * 32 + mt * 16 + q * 4) ^ ((tok & 7) << 3);
          *(uint2*)(hs + si) = make_uint2(u0, u1);
        }
      }
      if (r8 < 7) {
        *(short8*)(WS[iSp] + t * 16) = sa;
        *(short8*)(WS[iSp] + t * 16 + 8) = sb;
      }
      __syncthreads();
      // ---- G2: acc2 += W2q-frag MFMA hs ----
      short8 ta, tb;
      if (r8 < 7) {
        const unsigned short* ns2 = W2F + (((r8 + 1 < 4) ? eA : eB) * 4 + ((r8 + 1) & 3)) * 8192;
        ta = *(const short8*)(ns2 + t * 16);
        tb = *(const short8*)(ns2 + t * 16 + 8);
      }
      #pragma unroll
      for (int kl = 0; kl < 2; kl++) {
        short8 af[4];
        #pragma unroll
        for (int mt = 0; mt < 4; mt++)
          af[mt] = *(const short8*)(WS[iW2] + ((kl * 4 + q) * 128 + wh * 64 + mt * 16 + n16) * 8);
        short8 bh[4];
        #pragma unroll
        for (int nt = 0; nt < 4; nt++) {
          int tok = wt * 64 + nt * 16 + n16;
          bh[nt] = *(const short8*)(hs + ((tok * 64 + kl * 32 + q * 8) ^ ((tok & 7) << 3)));
        }
        #pragma unroll
        for (int nt = 0; nt < 4; nt++)
          #pragma unroll
          for (int mt = 0; mt < 4; mt++)
            acc2[mt][nt] = __builtin_amdgcn_mfma_f32_16x16x32_bf16(af[mt], bh[nt], acc2[mt][nt], 0, 0, 0);
      }
      if (r8 < 7) {
        *(short8*)(WS[iW1] + t * 16) = ta;
        *(short8*)(WS[iW1] + t * 16 + 8) = tb;
      }
      __syncthreads();
    }
    // ---- store: out[tok][oc] = acc2 + wA*b2A + wB*b2B ----
    #pragma unroll
    for (int mt = 0; mt < 4; mt++) {
      float4 b2a = *(const float4*)&b2L[wh * 64 + mt * 16 + q * 4];
      float4 b2b = *(const float4*)&b2L[128 + wh * 64 + mt * 16 + q * 4];
      #pragma unroll
      for (int nt = 0; nt < 4; nt++) {
        int tok = wt * 64 + nt * 16 + n16;
        if (tok < cval) {
          float wA = wabL[tok], wB = wabL[256 + tok];
          float4 v;
          v.x = acc2[mt][nt][0] + wA * b2a.x + wB * b2b.x;
          v.y = acc2[mt][nt][1] + wA * b2a.y + wB * b2b.y;
          v.z = acc2[mt][nt][2] + wA * b2a.z + wB * b2b.z;
          v.w = acc2[mt][nt][3] + wA * b2a.w + wB * b2b.w;
          *(float4*)(out + (size_t)toks[tok] * DOUT + wh * 64 + mt * 16 + q * 4) = v;
        }
      }
    }
    __syncthreads();   // toks/xs/wab reused next tile iteration
  }
}

extern "C" void kernel_launch(void* const* d_in, const int* in_sizes, int n_in,
                              void* d_out, int out_size, void* d_ws, size_t ws_size,
                              hipStream_t stream) {
  const float* x  = (const float*)d_in[0];
  const float* Wp = (const float*)d_in[1];
  const float* bp = (const float*)d_in[2];
  const float* Ee = (const float*)d_in[3];
  const float* W1 = (const float*)d_in[4];
  const float* b1 = (const float*)d_in[5];
  const float* W2 = (const float*)d_in[6];
  const float* b2 = (const float*)d_in[7];
  float* out = (float*)d_out;
  char* ws = (char*)d_ws;
  int* cnt = (int*)(ws + OFF_CNT);
  float* Wg = (float*)(ws + OFF_WG);
  float* bg = (float*)(ws + OFF_BG);
  unsigned short* W1F = (unsigned short*)(ws + OFF_W1F);
  unsigned short* W2F = (unsigned short*)(ws + OFF_W2F);
  uint4* lst = (uint4*)(ws + OFF_L);
  float* aux = out + (size_t)NTOK * DOUT;     // scalar output
  float* pout = aux + 1;                      // p_open [N,8]

  k_prep<<<65, 256, 0, stream>>>(W1, W2, W1F, W2F, Wp, bp, Ee, Wg, bg, cnt, aux);
  k_gate<<<NTOK / 512, 512, 0, stream>>>(x, Wg, bg, pout, cnt, lst);
  k_expert<<<NBEXP, 512, 0, stream>>>(x, W1F, W2F, b1, b2, cnt, lst, out);
}

// Round 5
// 163.275 us; speedup vs baseline: 1.0378x; 1.0378x over previous
//
#include <hip/hip_runtime.h>

#define NTOK 65536
#define DIN 128
#define DH 256
#define DOUT 128
#define NEXP 8
#define NPAIR 28
#define CAP 12288
#define TBL 1052      // 64-token tiles: 65536/64 + 28 partials
#define TAUF 5.0f
#define CSTRIDE 32    // cnt padded: one counter per 128 B

typedef __attribute__((ext_vector_type(8))) short short8;
typedef __attribute__((ext_vector_type(4))) float f32x4;

// ---- workspace layout (bytes) ----
#define OFF_CNT  0                              // 28 ints @ stride 32 ints
#define OFF_WG   4096                           // 1024 f32
#define OFF_BG   8192                           // 8 f32
#define OFF_W1F  8448                           // 8*128*256 bf16 = 524288
#define OFF_W2F  (OFF_W1F + NEXP*DIN*DH*2)      // 524288
#define OFF_L    (OFF_W2F + NEXP*DH*DOUT*2)     // 28*12288*16 = 5505024

__device__ __forceinline__ unsigned short f2bf(float f) {
  union { float f; unsigned u; } v; v.f = f;
  unsigned u = v.u;
  return (unsigned short)((u + 0x7FFFu + ((u >> 16) & 1u)) >> 16);
}

// ---- kernel 1: weight conversion (blocks 0..95) + gate fuse + cnt/aux zero (block 96) ----
// W1F layout: [e][kk 4][hc 256][kl 32]; W2F layout: [e][kk 8][oc 128][kl 32]
__global__ void k_prep(const float* __restrict__ W1, const float* __restrict__ W2,
                       unsigned short* __restrict__ W1F, unsigned short* __restrict__ W2F,
                       const float* __restrict__ Wp, const float* __restrict__ bp,
                       const float* __restrict__ Ee, float* __restrict__ Wg,
                       float* __restrict__ bg, int* __restrict__ cnt,
                       float* __restrict__ aux) {
  __shared__ float sl[8704];
  int b = blockIdx.x, t = threadIdx.x;
  if (b == 96) {
    for (int i = 0; i < 32; i++) sl[t + i * 256] = Wp[t + i * 256];
    sl[8192 + t] = Ee[t];
    sl[8448 + t] = Ee[256 + t];
    __syncthreads();
    for (int i = 0; i < 4; i++) {
      int o = t + i * 256;
      int k = o >> 3, e = o & 7;
      float s = 0.f;
      #pragma unroll 8
      for (int l = 0; l < 64; l++) s += sl[k * 64 + l] * sl[8192 + l * 8 + e];
      Wg[o] = s;
    }
    if (t < 8) {
      float s = 0.f;
      for (int l = 0; l < 64; l++) s += bp[l] * sl[8192 + l * 8 + t];
      bg[t] = s;
    }
    if (t < NPAIR) cnt[t * CSTRIDE] = 0;
    if (t == 255) aux[0] = 0.f;
    return;
  }
  const float* src; unsigned short* dst;
  int stride, iters, cshift;
  if (b < 32) {
    int e = b >> 2, kk = b & 3;
    src = W1 + e * (DIN * DH) + kk * 32 * DH;
    dst = W1F + e * (DIN * DH) + kk * (32 * DH);
    stride = 257; iters = 32; cshift = 8;           // 32 x 256 slab
  } else {
    int bb = b - 32;
    int e = bb >> 3, kk = bb & 7;
    src = W2 + e * (DH * DOUT) + kk * 32 * DOUT;
    dst = W2F + e * (DH * DOUT) + kk * (32 * DOUT);
    stride = 129; iters = 16; cshift = 7;           // 32 x 128 slab
  }
  int ncols_m1 = (1 << cshift) - 1;
  for (int i = 0; i < iters; i++) {
    int idx = t + i * 256;
    int r = idx >> cshift, c = idx & ncols_m1;
    sl[r * stride + c] = src[idx];
  }
  __syncthreads();
  for (int i = 0; i < iters; i++) {
    int o = t + i * 256;                            // o = n*32 + c : frag linear
    int n = o >> 5, cc = o & 31;
    dst[o] = f2bf(sl[cc * stride + n]);
  }
}

// ---- kernel 2: gate — thread-per-token (256 blocks x 256 tokens) ----
__global__ void __launch_bounds__(256) k_gate(
    const float* __restrict__ x, const float* __restrict__ Wg, const float* __restrict__ bg,
    float* __restrict__ pout, int* __restrict__ cnt, uint4* __restrict__ lst) {
  __shared__ float wgl[1024];
  __shared__ float bgl[8];
  __shared__ int lc[NPAIR], lb[NPAIR];
  int t = threadIdx.x, b = blockIdx.x;
  int tok = b * 256 + t;
  *(float4*)&wgl[t * 4] = ((const float4*)Wg)[t];
  if (t < 8) bgl[t] = bg[t];
  if (t < NPAIR) lc[t] = 0;
  __syncthreads();
  float acc[8];
  #pragma unroll
  for (int e = 0; e < 8; e++) acc[e] = bgl[e];
  const float4* xr = (const float4*)(x + (size_t)tok * DIN);
  #pragma unroll 4
  for (int i = 0; i < 32; i++) {
    float4 xv = xr[i];
    #pragma unroll
    for (int j = 0; j < 4; j++) {
      float xs_ = (j == 0) ? xv.x : (j == 1) ? xv.y : (j == 2) ? xv.z : xv.w;
      float4 wa = *(const float4*)&wgl[(i * 4 + j) * 8];
      float4 wb = *(const float4*)&wgl[(i * 4 + j) * 8 + 4];
      acc[0] += xs_ * wa.x; acc[1] += xs_ * wa.y; acc[2] += xs_ * wa.z; acc[3] += xs_ * wa.w;
      acc[4] += xs_ * wb.x; acc[5] += xs_ * wb.y; acc[6] += xs_ * wb.z; acc[7] += xs_ * wb.w;
    }
  }
  float p[8];
  #pragma unroll
  for (int e = 0; e < 8; e++) p[e] = 1.f / (1.f + expf(-acc[e] / TAUF));
  float* prow = pout + (size_t)tok * 8;
  #pragma unroll
  for (int e = 0; e < 8; e++) prow[e] = p[e];
  int i0 = 0; float v0 = -1.f;
  #pragma unroll
  for (int e = 0; e < 8; e++) if (p[e] > v0) { v0 = p[e]; i0 = e; }
  int i1 = -1; float v1 = -1.f;
  #pragma unroll
  for (int e = 0; e < 8; e++) if (e != i0 && p[e] > v1) { v1 = p[e]; i1 = e; }
  float s = v0 + v1 + 1e-10f;
  float w0 = v0 / s, w1 = v1 / s;
  int eA, eB; float wA, wB;
  if (i0 < i1) { eA = i0; eB = i1; wA = w0; wB = w1; }
  else         { eA = i1; eB = i0; wA = w1; wB = w0; }
  int pid = 7 * eA - (eA * (eA - 1)) / 2 + (eB - eA - 1);   // 28 unordered pairs
  union { float f; unsigned u; } ua, ub; ua.f = wA; ub.f = wB;
  unsigned wAb = ua.u, wBb = ub.u;
  unsigned pos = (unsigned)atomicAdd(&lc[pid], 1);   // LDS atomic
  __syncthreads();
  if (t < NPAIR) lb[t] = atomicAdd(&cnt[t * CSTRIDE], lc[t]);
  __syncthreads();
  int gi = lb[pid] + (int)pos;
  if (gi < CAP) lst[pid * CAP + gi] = make_uint4((unsigned)tok, wAb, wBb, 0u);
}

// ---- kernel 3: expert v7 — M=64 tiles, expert-split waves, DH-halved rounds.
// Waves 0-1 = expert A, 2-3 = expert B (wl = hidden/out half). Weights stream
// global->VGPR (4 KB/token, 271 MB total = half of v2); tokens/H go through LDS.
// H pre-scaled by gate weight so combine = LDS-staged add. LDS 53 KB -> 3 blocks/CU.
// acc1 mt-subchunked (peak ~135 VGPR, no spill under (256,3) cap). 7 barriers/block. ----
__global__ void __launch_bounds__(256, 3) k_expert(
    const float* __restrict__ x,
    const unsigned short* __restrict__ W1F, const unsigned short* __restrict__ W2F,
    const float* __restrict__ b1, const float* __restrict__ b2,
    const int* __restrict__ cnt, const uint4* __restrict__ lst,
    float* __restrict__ out) {
  __shared__ __align__(16) unsigned short xs[64 * 136];     // 17408 B
  __shared__ __align__(16) unsigned short hsb[2][64 * 136]; // 2 x 17408 B (per-expert H half)
  __shared__ int toks[64];
  __shared__ float wabL[128];                               // [0..63]=wA, [64..127]=wB
  int t = threadIdx.x;
  int w = t >> 6, lane = t & 63;
  int q = lane >> 4, n16 = lane & 15;
  int we = w >> 1, wl = w & 1;   // we: 0=expert A waves, 1=expert B waves

  int gid = blockIdx.x;
  int bsel = -1, tIn = 0, cntb = 0, cum = 0;
  #pragma unroll
  for (int bb = 0; bb < NPAIR; bb++) {
    int c = cnt[bb * CSTRIDE]; c = (c > CAP) ? CAP : c;   // uniform -> s_loads
    int tb = (c + 63) >> 6;
    if (bsel < 0 && gid < cum + tb) { bsel = bb; tIn = gid - cum; cntb = c; }
    cum += tb;
  }
  if (bsel < 0) return;
  int eA = 0, eB = 1;
  { int r = bsel;
    #pragma unroll
    for (int a = 0; a < 7; a++) { int span = 7 - a; if (r < span) { eA = a; eB = a + 1 + r; break; } r -= span; } }
  int start = tIn * 64;
  int cval = min(64, cntb - start);
  int e = we ? eB : eA;
  const unsigned short* W1e = W1F + e * (DIN * DH);
  const unsigned short* W2e = W2F + e * (DH * DOUT);
  unsigned short* hse = hsb[we];

  if (t < 64) {
    uint4 en = make_uint4(0u, 0u, 0u, 0u);
    if (t < cval) en = lst[bsel * CAP + start + t];
    toks[t] = (t < cval) ? (int)en.x : 0;
    union { unsigned u; float f; } ua, ub; ua.u = en.y; ub.u = en.z;
    wabL[t] = (t < cval) ? ua.f : 0.f;
    wabL[64 + t] = (t < cval) ? ub.f : 0.f;
  }
  // hoist rd=0,kk=0 W1 A-frags (token-independent; latency hides under gather)
  short8 af0[4];
  #pragma unroll
  for (int mt = 0; mt < 4; mt++)
    af0[mt] = *(const short8*)(W1e + (wl * 64 + mt * 16 + n16) * 32 + q * 8);
  __syncthreads();                                   // (1) toks/wab ready
  #pragma unroll
  for (int i = 0; i < 8; i++) {
    int idx = i * 256 + t;
    int r = idx >> 5, c4 = idx & 31;
    float4 f = *(const float4*)(x + (size_t)toks[r] * DIN + c4 * 4);
    unsigned u0 = (unsigned)f2bf(f.x) | ((unsigned)f2bf(f.y) << 16);
    unsigned u1 = (unsigned)f2bf(f.z) | ((unsigned)f2bf(f.w) << 16);
    *(uint2*)(xs + r * 136 + c4 * 4) = make_uint2(u0, u1);
  }
  __syncthreads();                                   // (2) xs ready
  const f32x4 vz = {0.f, 0.f, 0.f, 0.f};
  f32x4 acc2[4][4];                                  // [oc-tile][tok-tile], persists rounds
  #pragma unroll
  for (int mt = 0; mt < 4; mt++)
    #pragma unroll
    for (int nt = 0; nt < 4; nt++) acc2[mt][nt] = vz;

  #pragma unroll
  for (int rd = 0; rd < 2; rd++) {
    // ---- G1 half (swapped: D rows = hcol, cols = token): hs_e = w_e * relu(X@W1half + b1) ----
    #pragma unroll
    for (int mtc = 0; mtc < 2; mtc++) {
      f32x4 acc1[2][4];
      #pragma unroll
      for (int mi = 0; mi < 2; mi++)
        #pragma unroll
        for (int nt = 0; nt < 4; nt++) acc1[mi][nt] = vz;
      #pragma unroll
      for (int kk = 0; kk < 4; kk++) {
        short8 bx[4];
        #pragma unroll
        for (int nt = 0; nt < 4; nt++)
          bx[nt] = *(const short8*)(xs + (nt * 16 + n16) * 136 + kk * 32 + q * 8);
        #pragma unroll
        for (int mi = 0; mi < 2; mi++) {
          int mt = mtc * 2 + mi;
          short8 af = (rd == 0 && kk == 0)
              ? af0[mt]
              : *(const short8*)(W1e + kk * 8192 + (rd * 128 + wl * 64 + mt * 16 + n16) * 32 + q * 8);
          #pragma unroll
          for (int nt = 0; nt < 4; nt++)
            acc1[mi][nt] = __builtin_amdgcn_mfma_f32_16x16x32_bf16(af, bx[nt], acc1[mi][nt], 0, 0, 0);
        }
      }
      #pragma unroll
      for (int mi = 0; mi < 2; mi++) {
        int mt = mtc * 2 + mi;
        float4 b1f = *(const float4*)(b1 + e * DH + rd * 128 + wl * 64 + mt * 16 + q * 4);
        #pragma unroll
        for (int nt = 0; nt < 4; nt++) {
          int tok = nt * 16 + n16;
          float wv = wabL[we * 64 + tok];
          float v0 = fmaxf(acc1[mi][nt][0] + b1f.x, 0.f) * wv;
          float v1 = fmaxf(acc1[mi][nt][1] + b1f.y, 0.f) * wv;
          float v2 = fmaxf(acc1[mi][nt][2] + b1f.z, 0.f) * wv;
          float v3 = fmaxf(acc1[mi][nt][3] + b1f.w, 0.f) * wv;
          unsigned u0 = (unsigned)f2bf(v0) | ((unsigned)f2bf(v1) << 16);
          unsigned u1 = (unsigned)f2bf(v2) | ((unsigned)f2bf(v3) << 16);
          *(uint2*)(hse + tok * 136 + wl * 64 + mt * 16 + q * 4) = make_uint2(u0, u1);
        }
      }
    }
    __syncthreads();                                 // hs half ready (both wl waves)
    // ---- G2 half: acc2 += H_e(half) @ W2[rd-half K, own 64 oc] ----
    #pragma unroll
    for (int kk = 0; kk < 4; kk++) {
      short8 bh[4];
      #pragma unroll
      for (int nt = 0; nt < 4; nt++)
        bh[nt] = *(const short8*)(hse + (nt * 16 + n16) * 136 + kk * 32 + q * 8);
      #pragma unroll
      for (int mt = 0; mt < 4; mt++) {
        short8 af2 = *(const short8*)(W2e + (rd * 4 + kk) * 4096 + (wl * 64 + mt * 16 + n16) * 32 + q * 8);
        #pragma unroll
        for (int nt = 0; nt < 4; nt++)
          acc2[mt][nt] = __builtin_amdgcn_mfma_f32_16x16x32_bf16(af2, bh[nt], acc2[mt][nt], 0, 0, 0);
      }
    }
    __syncthreads();                                 // hs consumed (safe to overwrite / stage)
  }
  // ---- combine: A-waves stage weighted result; B-waves add + biases + store ----
  float* ostg = (float*)hsb[0];                      // 64 x 132 f32 = 33792 B (hsb = 34816 B)
  if (we == 0) {
    #pragma unroll
    for (int mt = 0; mt < 4; mt++)
      #pragma unroll
      for (int nt = 0; nt < 4; nt++) {
        int tok = nt * 16 + n16;
        *(f32x4*)&ostg[tok * 132 + wl * 64 + mt * 16 + q * 4] = acc2[mt][nt];
      }
  }
  __syncthreads();                                   // ostg ready
  if (we == 1) {
    #pragma unroll
    for (int mt = 0; mt < 4; mt++) {
      int oc0 = wl * 64 + mt * 16 + q * 4;
      float4 b2a = *(const float4*)(b2 + eA * DOUT + oc0);
      float4 b2b = *(const float4*)(b2 + eB * DOUT + oc0);
      #pragma unroll
      for (int nt = 0; nt < 4; nt++) {
        int tok = nt * 16 + n16;
        if (tok < cval) {
          float wA = wabL[tok], wB = wabL[64 + tok];
          float4 ro = *(const float4*)&ostg[tok * 132 + oc0];
          float4 v;
          v.x = ro.x + acc2[mt][nt][0] + wA * b2a.x + wB * b2b.x;
          v.y = ro.y + acc2[mt][nt][1] + wA * b2a.y + wB * b2b.y;
          v.z = ro.z + acc2[mt][nt][2] + wA * b2a.z + wB * b2b.z;
          v.w = ro.w + acc2[mt][nt][3] + wA * b2a.w + wB * b2b.w;
          *(float4*)(out + (size_t)toks[tok] * DOUT + oc0) = v;
        }
      }
    }
  }
}

extern "C" void kernel_launch(void* const* d_in, const int* in_sizes, int n_in,
                              void* d_out, int out_size, void* d_ws, size_t ws_size,
                              hipStream_t stream) {
  const float* x  = (const float*)d_in[0];
  const float* Wp = (const float*)d_in[1];
  const float* bp = (const float*)d_in[2];
  const float* Ee = (const float*)d_in[3];
  const float* W1 = (const float*)d_in[4];
  const float* b1 = (const float*)d_in[5];
  const float* W2 = (const float*)d_in[6];
  const float* b2 = (const float*)d_in[7];
  float* out = (float*)d_out;
  char* ws = (char*)d_ws;
  int* cnt = (int*)(ws + OFF_CNT);
  float* Wg = (float*)(ws + OFF_WG);
  float* bg = (float*)(ws + OFF_BG);
  unsigned short* W1F = (unsigned short*)(ws + OFF_W1F);
  unsigned short* W2F = (unsigned short*)(ws + OFF_W2F);
  uint4* lst = (uint4*)(ws + OFF_L);
  float* aux = out + (size_t)NTOK * DOUT;     // scalar output
  float* pout = aux + 1;                      // p_open [N,8]

  k_prep<<<97, 256, 0, stream>>>(W1, W2, W1F, W2F, Wp, bp, Ee, Wg, bg, cnt, aux);
  k_gate<<<NTOK / 256, 256, 0, stream>>>(x, Wg, bg, pout, cnt, lst);
  k_expert<<<TBL, 256, 0, stream>>>(x, W1F, W2F, b1, b2, cnt, lst, out);
}

// Round 6
// 152.937 us; speedup vs baseline: 1.1079x; 1.0676x over previous
//
#include <hip/hip_runtime.h>

#define NTOK 65536
#define DIN 128
#define DH 256
#define DOUT 128
#define NEXP 8
#define NPAIR 28
#define CAP 12288
#define TBL 2076      // 32-token tiles: 65536/32 + 28 partials
#define TAUF 5.0f
#define CSTRIDE 32    // cnt padded: one counter per 128 B

typedef __attribute__((ext_vector_type(8))) short short8;
typedef __attribute__((ext_vector_type(4))) float f32x4;

// ---- workspace layout (bytes) ----
#define OFF_CNT  0                              // 28 ints @ stride 32 ints
#define OFF_WG   4096                           // 1024 f32
#define OFF_BG   8192                           // 8 f32
#define OFF_W1F  8448                           // 8*128*256 bf16 = 524288
#define OFF_W2F  (OFF_W1F + NEXP*DIN*DH*2)      // 524288
#define OFF_L    (OFF_W2F + NEXP*DH*DOUT*2)     // 28*12288*16 = 5505024
// total ~6.6 MB

__device__ __forceinline__ unsigned short f2bf(float f) {
  union { float f; unsigned u; } v; v.f = f;
  unsigned u = v.u;
  return (unsigned short)((u + 0x7FFFu + ((u >> 16) & 1u)) >> 16);
}

// ---- kernel 1: weight conversion (blocks 0..95) + gate fuse + cnt/aux zero (block 96) ----
__global__ void k_prep(const float* __restrict__ W1, const float* __restrict__ W2,
                       unsigned short* __restrict__ W1F, unsigned short* __restrict__ W2F,
                       const float* __restrict__ Wp, const float* __restrict__ bp,
                       const float* __restrict__ Ee, float* __restrict__ Wg,
                       float* __restrict__ bg, int* __restrict__ cnt,
                       float* __restrict__ aux) {
  __shared__ float sl[8704];                    // >= 32*257 for conversion path
  int b = blockIdx.x, t = threadIdx.x;
  if (b == 96) {
    // stage Wp (8192 f) + Ee (512 f) into LDS, then compute Wg = Wp@Ee fused
    for (int i = 0; i < 32; i++) sl[t + i * 256] = Wp[t + i * 256];
    sl[8192 + t] = Ee[t];
    sl[8448 + t] = Ee[256 + t];
    __syncthreads();
    for (int i = 0; i < 4; i++) {
      int o = t + i * 256;
      int k = o >> 3, e = o & 7;
      float s = 0.f;
      #pragma unroll 8
      for (int l = 0; l < 64; l++) s += sl[k * 64 + l] * sl[8192 + l * 8 + e];
      Wg[o] = s;
    }
    if (t < 8) {
      float s = 0.f;
      for (int l = 0; l < 64; l++) s += bp[l] * sl[8192 + l * 8 + t];
      bg[t] = s;
    }
    if (t < NPAIR) cnt[t * CSTRIDE] = 0;
    if (t == 255) aux[0] = 0.f;
    return;
  }
  const float* src; unsigned short* dst;
  int stride, iters, cshift;
  if (b < 32) {
    int e = b >> 2, kk = b & 3;
    src = W1 + e * (DIN * DH) + kk * 32 * DH;
    dst = W1F + e * (DIN * DH) + kk * (32 * DH);
    stride = 257; iters = 32; cshift = 8;           // 32 x 256 slab
  } else {
    int bb = b - 32;
    int e = bb >> 3, kk = bb & 7;
    src = W2 + e * (DH * DOUT) + kk * 32 * DOUT;
    dst = W2F + e * (DH * DOUT) + kk * (32 * DOUT);
    stride = 129; iters = 16; cshift = 7;           // 32 x 128 slab
  }
  int ncols_m1 = (1 << cshift) - 1;
  for (int i = 0; i < iters; i++) {
    int idx = t + i * 256;
    int r = idx >> cshift, c = idx & ncols_m1;
    sl[r * stride + c] = src[idx];
  }
  __syncthreads();
  for (int i = 0; i < iters; i++) {
    int o = t + i * 256;                            // o = n*32 + c : B-frag linear
    int n = o >> 5, cc = o & 31;
    dst[o] = f2bf(sl[cc * stride + n]);
  }
}

// ---- kernel 2: gate — thread-per-token (256 blocks x 256 tokens) ----
__global__ void __launch_bounds__(256) k_gate(
    const float* __restrict__ x, const float* __restrict__ Wg, const float* __restrict__ bg,
    float* __restrict__ pout, int* __restrict__ cnt, uint4* __restrict__ lst) {
  __shared__ float wgl[1024];
  __shared__ float bgl[8];
  __shared__ int lc[NPAIR], lb[NPAIR];
  int t = threadIdx.x, b = blockIdx.x;
  int tok = b * 256 + t;
  *(float4*)&wgl[t * 4] = ((const float4*)Wg)[t];
  if (t < 8) bgl[t] = bg[t];
  if (t < NPAIR) lc[t] = 0;
  __syncthreads();
  float acc[8];
  #pragma unroll
  for (int e = 0; e < 8; e++) acc[e] = bgl[e];
  const float4* xr = (const float4*)(x + (size_t)tok * DIN);
  #pragma unroll 4
  for (int i = 0; i < 32; i++) {
    float4 xv = xr[i];
    #pragma unroll
    for (int j = 0; j < 4; j++) {
      float xs_ = (j == 0) ? xv.x : (j == 1) ? xv.y : (j == 2) ? xv.z : xv.w;
      float4 wa = *(const float4*)&wgl[(i * 4 + j) * 8];
      float4 wb = *(const float4*)&wgl[(i * 4 + j) * 8 + 4];
      acc[0] += xs_ * wa.x; acc[1] += xs_ * wa.y; acc[2] += xs_ * wa.z; acc[3] += xs_ * wa.w;
      acc[4] += xs_ * wb.x; acc[5] += xs_ * wb.y; acc[6] += xs_ * wb.z; acc[7] += xs_ * wb.w;
    }
  }
  float p[8];
  #pragma unroll
  for (int e = 0; e < 8; e++) p[e] = 1.f / (1.f + expf(-acc[e] / TAUF));
  float* prow = pout + (size_t)tok * 8;
  #pragma unroll
  for (int e = 0; e < 8; e++) prow[e] = p[e];
  int i0 = 0; float v0 = -1.f;
  #pragma unroll
  for (int e = 0; e < 8; e++) if (p[e] > v0) { v0 = p[e]; i0 = e; }
  int i1 = -1; float v1 = -1.f;
  #pragma unroll
  for (int e = 0; e < 8; e++) if (e != i0 && p[e] > v1) { v1 = p[e]; i1 = e; }
  float s = v0 + v1 + 1e-10f;
  float w0 = v0 / s, w1 = v1 / s;
  int eA, eB; float wA, wB;
  if (i0 < i1) { eA = i0; eB = i1; wA = w0; wB = w1; }
  else         { eA = i1; eB = i0; wA = w1; wB = w0; }
  int pid = 7 * eA - (eA * (eA - 1)) / 2 + (eB - eA - 1);   // 28 unordered pairs
  union { float f; unsigned u; } ua, ub; ua.f = wA; ub.f = wB;
  unsigned wAb = ua.u, wBb = ub.u;
  unsigned pos = (unsigned)atomicAdd(&lc[pid], 1);   // LDS atomic
  __syncthreads();
  if (t < NPAIR) lb[t] = atomicAdd(&cnt[t * CSTRIDE], lc[t]);
  __syncthreads();
  int gi = lb[pid] + (int)pos;
  if (gi < CAP) lst[pid * CAP + gi] = make_uint4((unsigned)tok, wAb, wBb, 0u);
}

// ---- kernel 3: expert v2 + ILP fix — 32-token tiles, pass-0 B-panel hoist.
// ONE change vs round-1 best (49.4 us): __launch_bounds__(256,2) instead of (256,4).
// Theory: the (256,4) 64-VGPR cap could not hold the 16-deep B-panel load queue
// (16 x short8 = 64 VGPR alone) -> compiler strip-mined panel loads to ~4-in-flight,
// serializing L2/L3 round-trips. 128-VGPR cap restores 16-in-flight; LDS (26 KB)
// still allows 4+ blocks/CU so residency stays ~unchanged. ----
__global__ void __launch_bounds__(256, 2) k_expert(
    const float* __restrict__ x,
    const unsigned short* __restrict__ W1F, const unsigned short* __restrict__ W2F,
    const float* __restrict__ b1, const float* __restrict__ b2,
    const int* __restrict__ cnt, const uint4* __restrict__ lst,
    float* __restrict__ out) {
  __shared__ int cs[NPAIR];
  __shared__ int toks[32];
  __shared__ float wAs[32], wBs[32];
  __shared__ unsigned short xs[32 * 136];   // 8704 B
  __shared__ unsigned short hs[32 * 264];   // 16896 B
  int t = threadIdx.x;
  if (t < NPAIR) cs[t] = cnt[t * CSTRIDE];
  __syncthreads();
  int gid = blockIdx.x;
  int bsel = -1, tIn = 0, cum = 0;
  #pragma unroll
  for (int bb = 0; bb < NPAIR; bb++) {
    int c = cs[bb]; c = (c > CAP) ? CAP : c;
    int tb = (c + 31) >> 5;
    if (bsel < 0 && gid < cum + tb) { bsel = bb; tIn = gid - cum; }
    cum += tb;
  }
  if (bsel < 0) return;
  int eA = 0, eB = 1;
  { int r = bsel;
    #pragma unroll
    for (int a = 0; a < 7; a++) { int span = 7 - a; if (r < span) { eA = a; eB = a + 1 + r; break; } r -= span; } }
  int cntb = cs[bsel]; cntb = (cntb > CAP) ? CAP : cntb;
  int start = tIn * 32;
  int cvalid = min(32, cntb - start);

  int lane = t & 63, w = t >> 6;
  int q = lane >> 4, n16 = lane & 15;

  // hoist pass-0 GEMM1 B-panel: issue now, consumed after gather barrier
  short8 bf0[16];
  {
    const unsigned short* Bp = W1F + eA * (DIN * DH) + (w * 64 + n16) * 32 + q * 8;
    #pragma unroll
    for (int kk = 0; kk < 4; kk++)
      #pragma unroll
      for (int nt = 0; nt < 4; nt++)
        bf0[kk * 4 + nt] = *(const short8*)(Bp + kk * 8192 + nt * 512);
  }

  if (t < 32) {
    if (t < cvalid) {
      uint4 en = lst[bsel * CAP + start + t];
      toks[t] = (int)en.x;
      union { unsigned u; float f; } ua, ub; ua.u = en.y; ub.u = en.z;
      wAs[t] = ua.f; wBs[t] = ub.f;
    } else { toks[t] = 0; wAs[t] = 0.f; wBs[t] = 0.f; }
  }
  __syncthreads();
  for (int i = 0; i < 4; i++) {          // gather x rows -> bf16 LDS (32 rows)
    int idx = i * 256 + t;
    int r = idx >> 5, c4 = idx & 31;
    float4 f = *(const float4*)(x + (size_t)toks[r] * DIN + c4 * 4);
    unsigned u0 = (unsigned)f2bf(f.x) | ((unsigned)f2bf(f.y) << 16);
    unsigned u1 = (unsigned)f2bf(f.z) | ((unsigned)f2bf(f.w) << 16);
    *(uint2*)(xs + r * 136 + c4 * 4) = make_uint2(u0, u1);
  }
  __syncthreads();
  const f32x4 vz = {0.f, 0.f, 0.f, 0.f};
  int cb = w * 32;                      // GEMM2: wave w owns cols [32w, 32w+32)
  f32x4 accO[2][2];
  #pragma unroll
  for (int pass = 0; pass < 2; pass++) {
    int e = pass ? eB : eA;
    if (pass) __syncthreads();   // all waves done reading hs from pass 0
    // ---- GEMM1: H = relu(X @ W1[e] + b1[e]); wave w -> hidden cols [w*64, +64) ----
    {
      short8 bf[16];
      if (pass == 0) {
        #pragma unroll
        for (int i = 0; i < 16; i++) bf[i] = bf0[i];
      } else {
        const unsigned short* Bp = W1F + e * (DIN * DH) + (w * 64 + n16) * 32 + q * 8;
        #pragma unroll
        for (int kk = 0; kk < 4; kk++)
          #pragma unroll
          for (int nt = 0; nt < 4; nt++)
            bf[kk * 4 + nt] = *(const short8*)(Bp + kk * 8192 + nt * 512);
      }
      float b1v[4];
      #pragma unroll
      for (int nt = 0; nt < 4; nt++) b1v[nt] = b1[e * DH + w * 64 + nt * 16 + n16];
      f32x4 acc[2][4];
      #pragma unroll
      for (int mt = 0; mt < 2; mt++)
        #pragma unroll
        for (int nt = 0; nt < 4; nt++) acc[mt][nt] = vz;
      #pragma unroll
      for (int kk = 0; kk < 4; kk++) {
        short8 a[2];
        #pragma unroll
        for (int mt = 0; mt < 2; mt++)
          a[mt] = *(const short8*)(xs + (mt * 16 + n16) * 136 + kk * 32 + q * 8);
        #pragma unroll
        for (int nt = 0; nt < 4; nt++)
          #pragma unroll
          for (int mt = 0; mt < 2; mt++)
            acc[mt][nt] = __builtin_amdgcn_mfma_f32_16x16x32_bf16(a[mt], bf[kk * 4 + nt], acc[mt][nt], 0, 0, 0);
      }
      #pragma unroll
      for (int mt = 0; mt < 2; mt++)
        #pragma unroll
        for (int nt = 0; nt < 4; nt++)
          #pragma unroll
          for (int r = 0; r < 4; r++) {
            float v = fmaxf(acc[mt][nt][r] + b1v[nt], 0.f);
            hs[(mt * 16 + q * 4 + r) * 264 + w * 64 + nt * 16 + n16] = f2bf(v);
          }
    }
    // prefetch GEMM2 B-panel (independent of hs) -- completes across the barrier
    short8 bf2[16];                     // 32 cols x 256 k: 16 loads in flight
    {
      const unsigned short* Bp2 = W2F + e * (DH * DOUT) + (cb + n16) * 32 + q * 8;
      #pragma unroll
      for (int kk = 0; kk < 8; kk++)
        #pragma unroll
        for (int nt = 0; nt < 2; nt++)
          bf2[kk * 2 + nt] = *(const short8*)(Bp2 + kk * 4096 + nt * 512);
    }
    __syncthreads();
    // ---- GEMM2: acc2 = H @ W2[e]; wave w -> all 32 rows, cols [w*32, +32) ----
    {
      float b2v[2];
      #pragma unroll
      for (int nt = 0; nt < 2; nt++) b2v[nt] = b2[e * DOUT + cb + nt * 16 + n16];
      f32x4 acc2[2][2];
      #pragma unroll
      for (int m = 0; m < 2; m++)
        #pragma unroll
        for (int nt = 0; nt < 2; nt++) acc2[m][nt] = vz;
      #pragma unroll
      for (int kk = 0; kk < 8; kk++) {
        short8 a[2];
        #pragma unroll
        for (int m = 0; m < 2; m++)
          a[m] = *(const short8*)(hs + (m * 16 + n16) * 264 + kk * 32 + q * 8);
        #pragma unroll
        for (int nt = 0; nt < 2; nt++)
          #pragma unroll
          for (int m = 0; m < 2; m++)
            acc2[m][nt] = __builtin_amdgcn_mfma_f32_16x16x32_bf16(a[m], bf2[kk * 2 + nt], acc2[m][nt], 0, 0, 0);
      }
      const float* wsel = pass ? wBs : wAs;
      #pragma unroll
      for (int m = 0; m < 2; m++)
        #pragma unroll
        for (int r = 0; r < 4; r++) {
          float wv = wsel[m * 16 + q * 4 + r];
          #pragma unroll
          for (int nt = 0; nt < 2; nt++) {
            float v = (acc2[m][nt][r] + b2v[nt]) * wv;
            if (pass) accO[m][nt][r] += v;
            else      accO[m][nt][r] = v;
          }
        }
    }
  }
  // single store per output element (wave w -> cols [32w,+32), all rows)
  #pragma unroll
  for (int m = 0; m < 2; m++)
    #pragma unroll
    for (int r = 0; r < 4; r++) {
      int row = m * 16 + q * 4 + r;
      if (row < cvalid) {
        float* orow = out + (size_t)toks[row] * DOUT + cb + n16;
        orow[0]  = accO[m][0][r];
        orow[16] = accO[m][1][r];
      }
    }
}

extern "C" void kernel_launch(void* const* d_in, const int* in_sizes, int n_in,
                              void* d_out, int out_size, void* d_ws, size_t ws_size,
                              hipStream_t stream) {
  const float* x  = (const float*)d_in[0];
  const float* Wp = (const float*)d_in[1];
  const float* bp = (const float*)d_in[2];
  const float* Ee = (const float*)d_in[3];
  const float* W1 = (const float*)d_in[4];
  const float* b1 = (const float*)d_in[5];
  const float* W2 = (const float*)d_in[6];
  const float* b2 = (const float*)d_in[7];
  float* out = (float*)d_out;
  char* ws = (char*)d_ws;
  int* cnt = (int*)(ws + OFF_CNT);
  float* Wg = (float*)(ws + OFF_WG);
  float* bg = (float*)(ws + OFF_BG);
  unsigned short* W1F = (unsigned short*)(ws + OFF_W1F);
  unsigned short* W2F = (unsigned short*)(ws + OFF_W2F);
  uint4* lst = (uint4*)(ws + OFF_L);
  float* aux = out + (size_t)NTOK * DOUT;     // scalar output
  float* pout = aux + 1;                      // p_open [N,8]

  k_prep<<<97, 256, 0, stream>>>(W1, W2, W1F, W2F, Wp, bp, Ee, Wg, bg, cnt, aux);
  k_gate<<<NTOK / 256, 256, 0, stream>>>(x, Wg, bg, pout, cnt, lst);
  k_expert<<<TBL, 256, 0, stream>>>(x, W1F, W2F, b1, b2, cnt, lst, out);
}

// Round 7
// 151.099 us; speedup vs baseline: 1.1214x; 1.0122x over previous
//
#include <hip/hip_runtime.h>

#define NTOK 65536
#define DIN 128
#define DH 256
#define DOUT 128
#define NEXP 8
#define NPAIR 28
#define CAP 12288
#define TBL2 540      // 128-token tiles: 65536/128 + 28 partials
#define TAUF 5.0f
#define CSTRIDE 32    // cnt padded: one counter per 128 B

typedef __attribute__((ext_vector_type(8))) short short8;
typedef __attribute__((ext_vector_type(4))) float f32x4;

// ---- workspace layout (bytes) ----
#define OFF_CNT  0                              // 28 ints @ stride 32 ints
#define OFF_WG   4096                           // 1024 f32
#define OFF_BG   8192                           // 8 f32
#define OFF_W1F  8448                           // 8*128*256 bf16 = 524288
#define OFF_W2F  (OFF_W1F + NEXP*DIN*DH*2)      // 524288
#define OFF_L    (OFF_W2F + NEXP*DH*DOUT*2)     // 28*12288*16 = 5505024
// total ~6.6 MB

__device__ __forceinline__ unsigned short f2bf(float f) {
  union { float f; unsigned u; } v; v.f = f;
  unsigned u = v.u;
  return (unsigned short)((u + 0x7FFFu + ((u >> 16) & 1u)) >> 16);
}

// packed f32x2 -> bf16x2 (RNE), single HW instr (T12); lo = first operand
__device__ __forceinline__ unsigned pkbf(float a, float b) {
  unsigned r;
  asm("v_cvt_pk_bf16_f32 %0, %1, %2" : "=v"(r) : "v"(a), "v"(b));
  return r;
}

// ---- kernel 1: weight conversion (blocks 0..95) + gate fuse + cnt/aux zero (block 96) ----
__global__ void k_prep(const float* __restrict__ W1, const float* __restrict__ W2,
                       unsigned short* __restrict__ W1F, unsigned short* __restrict__ W2F,
                       const float* __restrict__ Wp, const float* __restrict__ bp,
                       const float* __restrict__ Ee, float* __restrict__ Wg,
                       float* __restrict__ bg, int* __restrict__ cnt,
                       float* __restrict__ aux) {
  __shared__ float sl[8704];                    // >= 32*257 for conversion path
  int b = blockIdx.x, t = threadIdx.x;
  if (b == 96) {
    for (int i = 0; i < 32; i++) sl[t + i * 256] = Wp[t + i * 256];
    sl[8192 + t] = Ee[t];
    sl[8448 + t] = Ee[256 + t];
    __syncthreads();
    for (int i = 0; i < 4; i++) {
      int o = t + i * 256;
      int k = o >> 3, e = o & 7;
      float s = 0.f;
      #pragma unroll 8
      for (int l = 0; l < 64; l++) s += sl[k * 64 + l] * sl[8192 + l * 8 + e];
      Wg[o] = s;
    }
    if (t < 8) {
      float s = 0.f;
      for (int l = 0; l < 64; l++) s += bp[l] * sl[8192 + l * 8 + t];
      bg[t] = s;
    }
    if (t < NPAIR) cnt[t * CSTRIDE] = 0;
    if (t == 255) aux[0] = 0.f;
    return;
  }
  const float* src; unsigned short* dst;
  int stride, iters, cshift;
  if (b < 32) {
    int e = b >> 2, kk = b & 3;
    src = W1 + e * (DIN * DH) + kk * 32 * DH;
    dst = W1F + e * (DIN * DH) + kk * (32 * DH);
    stride = 257; iters = 32; cshift = 8;           // 32 x 256 slab
  } else {
    int bb = b - 32;
    int e = bb >> 3, kk = bb & 7;
    src = W2 + e * (DH * DOUT) + kk * 32 * DOUT;
    dst = W2F + e * (DH * DOUT) + kk * (32 * DOUT);
    stride = 129; iters = 16; cshift = 7;           // 32 x 128 slab
  }
  int ncols_m1 = (1 << cshift) - 1;
  for (int i = 0; i < iters; i++) {
    int idx = t + i * 256;
    int r = idx >> cshift, c = idx & ncols_m1;
    sl[r * stride + c] = src[idx];
  }
  __syncthreads();
  for (int i = 0; i < iters; i++) {
    int o = t + i * 256;                            // o = n*32 + c : frag linear
    int n = o >> 5, cc = o & 31;
    dst[o] = f2bf(sl[cc * stride + n]);
  }
}

// ---- kernel 2: gate — thread-per-token (256 blocks x 256 tokens), unchanged ----
__global__ void __launch_bounds__(256) k_gate(
    const float* __restrict__ x, const float* __restrict__ Wg, const float* __restrict__ bg,
    float* __restrict__ pout, int* __restrict__ cnt, uint4* __restrict__ lst) {
  __shared__ float wgl[1024];
  __shared__ float bgl[8];
  __shared__ int lc[NPAIR], lb[NPAIR];
  int t = threadIdx.x, b = blockIdx.x;
  int tok = b * 256 + t;
  *(float4*)&wgl[t * 4] = ((const float4*)Wg)[t];
  if (t < 8) bgl[t] = bg[t];
  if (t < NPAIR) lc[t] = 0;
  __syncthreads();
  float acc[8];
  #pragma unroll
  for (int e = 0; e < 8; e++) acc[e] = bgl[e];
  const float4* xr = (const float4*)(x + (size_t)tok * DIN);
  #pragma unroll 4
  for (int i = 0; i < 32; i++) {
    float4 xv = xr[i];
    #pragma unroll
    for (int j = 0; j < 4; j++) {
      float xs_ = (j == 0) ? xv.x : (j == 1) ? xv.y : (j == 2) ? xv.z : xv.w;
      float4 wa = *(const float4*)&wgl[(i * 4 + j) * 8];
      float4 wb = *(const float4*)&wgl[(i * 4 + j) * 8 + 4];
      acc[0] += xs_ * wa.x; acc[1] += xs_ * wa.y; acc[2] += xs_ * wa.z; acc[3] += xs_ * wa.w;
      acc[4] += xs_ * wb.x; acc[5] += xs_ * wb.y; acc[6] += xs_ * wb.z; acc[7] += xs_ * wb.w;
    }
  }
  float p[8];
  #pragma unroll
  for (int e = 0; e < 8; e++) p[e] = 1.f / (1.f + expf(-acc[e] / TAUF));
  float* prow = pout + (size_t)tok * 8;
  #pragma unroll
  for (int e = 0; e < 8; e++) prow[e] = p[e];
  int i0 = 0; float v0 = -1.f;
  #pragma unroll
  for (int e = 0; e < 8; e++) if (p[e] > v0) { v0 = p[e]; i0 = e; }
  int i1 = -1; float v1 = -1.f;
  #pragma unroll
  for (int e = 0; e < 8; e++) if (e != i0 && p[e] > v1) { v1 = p[e]; i1 = e; }
  float s = v0 + v1 + 1e-10f;
  float w0 = v0 / s, w1 = v1 / s;
  int eA, eB; float wA, wB;
  if (i0 < i1) { eA = i0; eB = i1; wA = w0; wB = w1; }
  else         { eA = i1; eB = i0; wA = w1; wB = w0; }
  int pid = 7 * eA - (eA * (eA - 1)) / 2 + (eB - eA - 1);   // 28 unordered pairs
  union { float f; unsigned u; } ua, ub; ua.f = wA; ub.f = wB;
  unsigned wAb = ua.u, wBb = ub.u;
  unsigned pos = (unsigned)atomicAdd(&lc[pid], 1);   // LDS atomic
  __syncthreads();
  if (t < NPAIR) lb[t] = atomicAdd(&cnt[t * CSTRIDE], lc[t]);
  __syncthreads();
  int gi = lb[pid] + (int)pos;
  if (gi < CAP) lst[pid * CAP + gi] = make_uint4((unsigned)tok, wAb, wBb, 0u);
}

// ---- kernel 3: expert v8 — M=128 token tiles, swapped-operand MFMA, DH-halved.
// 4 waves; GEMM1: wave w owns hcols [h*128+w*32,+32); GEMM2: ocols [w*32,+32).
// Weights global->VGPR, panel regs amortized over 8 token-16-tiles (128 MFMA per
// 8-16 panel loads vs v2's 32 per 16). H pre-scaled by gate weight; ONE acc2
// accumulated across both expert passes (no combine pass). hs writes packed uint2
// via v_cvt_pk_bf16_f32. LDS 71 KB -> 2 blocks/CU. ~10 barriers / 128 tokens. ----
__global__ void __launch_bounds__(256, 2) k_expert(
    const float* __restrict__ x,
    const unsigned short* __restrict__ W1F, const unsigned short* __restrict__ W2F,
    const float* __restrict__ b1, const float* __restrict__ b2,
    const int* __restrict__ cnt, const uint4* __restrict__ lst,
    float* __restrict__ out) {
  __shared__ int cs[NPAIR];
  __shared__ __align__(16) unsigned short xs[128 * 136];   // 34816 B
  __shared__ __align__(16) unsigned short hs[128 * 136];   // 34816 B (one DH-half)
  __shared__ int toks[128];
  __shared__ float wabL[256];                              // [0..127]=wA, [128..255]=wB
  int t = threadIdx.x;
  int w = t >> 6, lane = t & 63;
  int q = lane >> 4, n16 = lane & 15;

  if (t < NPAIR) { int c = cnt[t * CSTRIDE]; cs[t] = (c > CAP) ? CAP : c; }
  __syncthreads();
  int gid = blockIdx.x;
  int bsel = -1, tIn = 0, cum = 0;
  #pragma unroll
  for (int bb = 0; bb < NPAIR; bb++) {
    int tb = (cs[bb] + 127) >> 7;
    if (bsel < 0 && gid < cum + tb) { bsel = bb; tIn = gid - cum; }
    cum += tb;
  }
  if (bsel < 0) return;
  int eA = 0, eB = 1;
  { int r = bsel;
    #pragma unroll
    for (int a = 0; a < 7; a++) { int span = 7 - a; if (r < span) { eA = a; eB = a + 1 + r; break; } r -= span; } }
  int start = tIn * 128;
  int cval = min(128, cs[bsel] - start);

  if (t < 128) {
    uint4 en = make_uint4(0u, 0u, 0u, 0u);
    if (t < cval) en = lst[bsel * CAP + start + t];
    toks[t] = (t < cval) ? (int)en.x : 0;
    union { unsigned u; float f; } ua, ub; ua.u = en.y; ub.u = en.z;
    wabL[t] = (t < cval) ? ua.f : 0.f;
    wabL[128 + t] = (t < cval) ? ub.f : 0.f;
  }
  __syncthreads();
  // gather 128 x rows -> bf16 LDS
  #pragma unroll
  for (int i = 0; i < 16; i++) {
    int idx = i * 256 + t;
    int r = idx >> 5, c4 = idx & 31;
    float4 f = *(const float4*)(x + (size_t)toks[r] * DIN + c4 * 4);
    unsigned u0 = pkbf(f.x, f.y);
    unsigned u1 = pkbf(f.z, f.w);
    *(uint2*)(xs + r * 136 + c4 * 4) = make_uint2(u0, u1);
  }
  __syncthreads();

  const f32x4 vz = {0.f, 0.f, 0.f, 0.f};
  f32x4 acc2[8][2];                                // [tok-16-tile][oc-16-tile], both passes
  #pragma unroll
  for (int tc = 0; tc < 8; tc++)
    #pragma unroll
    for (int nt = 0; nt < 2; nt++) acc2[tc][nt] = vz;

  #pragma unroll
  for (int pass = 0; pass < 2; pass++) {
    int e = pass ? eB : eA;
    const unsigned short* W1e = W1F + e * (DIN * DH);
    const unsigned short* W2e = W2F + e * (DH * DOUT);
    #pragma unroll
    for (int h = 0; h < 2; h++) {
      // ---- GEMM1 half: H^T tile (rows=hcol, cols=token), hcols [h*128+w*32,+32) ----
      short8 af[4][2];
      #pragma unroll
      for (int kk = 0; kk < 4; kk++)
        #pragma unroll
        for (int nt = 0; nt < 2; nt++)
          af[kk][nt] = *(const short8*)(W1e + kk * 8192 + (h * 128 + w * 32 + nt * 16 + n16) * 32 + q * 8);
      float4 b1f[2];
      #pragma unroll
      for (int nt = 0; nt < 2; nt++)
        b1f[nt] = *(const float4*)(b1 + e * DH + h * 128 + w * 32 + nt * 16 + q * 4);
      #pragma unroll
      for (int tc = 0; tc < 8; tc++) {
        short8 bx[4];
        #pragma unroll
        for (int kk = 0; kk < 4; kk++)
          bx[kk] = *(const short8*)(xs + (tc * 16 + n16) * 136 + kk * 32 + q * 8);
        f32x4 a1[2];
        a1[0] = vz; a1[1] = vz;
        #pragma unroll
        for (int kk = 0; kk < 4; kk++)
          #pragma unroll
          for (int nt = 0; nt < 2; nt++)
            a1[nt] = __builtin_amdgcn_mfma_f32_16x16x32_bf16(af[kk][nt], bx[kk], a1[nt], 0, 0, 0);
        int tok = tc * 16 + n16;
        float wv = wabL[pass * 128 + tok];
        #pragma unroll
        for (int nt = 0; nt < 2; nt++) {
          unsigned u0 = pkbf(fmaxf(a1[nt][0] + b1f[nt].x, 0.f) * wv,
                             fmaxf(a1[nt][1] + b1f[nt].y, 0.f) * wv);
          unsigned u1 = pkbf(fmaxf(a1[nt][2] + b1f[nt].z, 0.f) * wv,
                             fmaxf(a1[nt][3] + b1f[nt].w, 0.f) * wv);
          *(uint2*)(hs + tok * 136 + w * 32 + nt * 16 + q * 4) = make_uint2(u0, u1);
        }
      }
      __syncthreads();                             // hs half ready
      // ---- GEMM2 half: acc2 += W2[h-half K] (x) H-half; ocols [w*32,+32) ----
      short8 bw[4][2];
      #pragma unroll
      for (int kk = 0; kk < 4; kk++)
        #pragma unroll
        for (int nt = 0; nt < 2; nt++)
          bw[kk][nt] = *(const short8*)(W2e + (h * 4 + kk) * 4096 + (w * 32 + nt * 16 + n16) * 32 + q * 8);
      #pragma unroll
      for (int tc = 0; tc < 8; tc++) {
        short8 bh[4];
        #pragma unroll
        for (int kk = 0; kk < 4; kk++)
          bh[kk] = *(const short8*)(hs + (tc * 16 + n16) * 136 + kk * 32 + q * 8);
        #pragma unroll
        for (int kk = 0; kk < 4; kk++)
          #pragma unroll
          for (int nt = 0; nt < 2; nt++)
            acc2[tc][nt] = __builtin_amdgcn_mfma_f32_16x16x32_bf16(bw[kk][nt], bh[kk], acc2[tc][nt], 0, 0, 0);
      }
      __syncthreads();                             // hs consumed before overwrite
    }
  }
  // ---- store: out[tok][oc] = acc2 + wA*b2A + wB*b2B (lane=token, float4 of ocols) ----
  float4 b2a[2], b2b[2];
  #pragma unroll
  for (int nt = 0; nt < 2; nt++) {
    b2a[nt] = *(const float4*)(b2 + eA * DOUT + w * 32 + nt * 16 + q * 4);
    b2b[nt] = *(const float4*)(b2 + eB * DOUT + w * 32 + nt * 16 + q * 4);
  }
  #pragma unroll
  for (int tc = 0; tc < 8; tc++) {
    int tok = tc * 16 + n16;
    if (tok < cval) {
      float wA = wabL[tok], wB = wabL[128 + tok];
      float* orow = out + (size_t)toks[tok] * DOUT + w * 32 + q * 4;
      #pragma unroll
      for (int nt = 0; nt < 2; nt++) {
        float4 v;
        v.x = acc2[tc][nt][0] + wA * b2a[nt].x + wB * b2b[nt].x;
        v.y = acc2[tc][nt][1] + wA * b2a[nt].y + wB * b2b[nt].y;
        v.z = acc2[tc][nt][2] + wA * b2a[nt].z + wB * b2b[nt].z;
        v.w = acc2[tc][nt][3] + wA * b2a[nt].w + wB * b2b[nt].w;
        *(float4*)(orow + nt * 16) = v;
      }
    }
  }
}

extern "C" void kernel_launch(void* const* d_in, const int* in_sizes, int n_in,
                              void* d_out, int out_size, void* d_ws, size_t ws_size,
                              hipStream_t stream) {
  const float* x  = (const float*)d_in[0];
  const float* Wp = (const float*)d_in[1];
  const float* bp = (const float*)d_in[2];
  const float* Ee = (const float*)d_in[3];
  const float* W1 = (const float*)d_in[4];
  const float* b1 = (const float*)d_in[5];
  const float* W2 = (const float*)d_in[6];
  const float* b2 = (const float*)d_in[7];
  float* out = (float*)d_out;
  char* ws = (char*)d_ws;
  int* cnt = (int*)(ws + OFF_CNT);
  float* Wg = (float*)(ws + OFF_WG);
  float* bg = (float*)(ws + OFF_BG);
  unsigned short* W1F = (unsigned short*)(ws + OFF_W1F);
  unsigned short* W2F = (unsigned short*)(ws + OFF_W2F);
  uint4* lst = (uint4*)(ws + OFF_L);
  float* aux = out + (size_t)NTOK * DOUT;     // scalar output
  float* pout = aux + 1;                      // p_open [N,8]

  k_prep<<<97, 256, 0, stream>>>(W1, W2, W1F, W2F, Wp, bp, Ee, Wg, bg, cnt, aux);
  k_gate<<<NTOK / 256, 256, 0, stream>>>(x, Wg, bg, pout, cnt, lst);
  k_expert<<<TBL2, 256, 0, stream>>>(x, W1F, W2F, b1, b2, cnt, lst, out);
}